// Round 4
// baseline (314.989 us; speedup 1.0000x reference)
//
#include <hip/hip_runtime.h>
#include <math.h>

#define D 64
#define K 512
#define N_TOK (32 * 4096)            // 131072 tokens
#define TOK_PER_BLK 256

// output layout (all f32, concatenated in reference return order)
#define Q_OFF    0
#define LOSS_OFF 8388608
#define PERP_OFF 8388609
#define ENC_OFF  8388610
#define MIND_OFF 8519682

// ws layout (floats): [0..511] b2[k] = np-f32 sum(e_k^2) ; [512] S_sq ; [513] S_mind ; [514..1025] counts(int)

// numpy pairwise_sum, n=64, scalar 8-accumulator path, on fl(x_i*x_i).
// r[j] = x[j]^2 + x[8+j]^2 + ... + x[56+j]^2 (sequential adds of rounded squares),
// result = ((r0+r1)+(r2+r3)) + ((r4+r5)+(r6+r7)). __f*_rn blocks fma contraction.
__device__ __forceinline__ float np_sumsq64(const float* x) {
    float r[8];
    #pragma unroll
    for (int j = 0; j < 8; ++j) r[j] = __fmul_rn(x[j], x[j]);
    #pragma unroll
    for (int i = 8; i < 64; i += 8) {
        #pragma unroll
        for (int j = 0; j < 8; ++j)
            r[j] = __fadd_rn(r[j], __fmul_rn(x[i + j], x[i + j]));
    }
    float l = __fadd_rn(__fadd_rn(r[0], r[1]), __fadd_rn(r[2], r[3]));
    float h = __fadd_rn(__fadd_rn(r[4], r[5]), __fadd_rn(r[6], r[7]));
    return __fadd_rn(l, h);
}

__global__ void vq_prep(const float* __restrict__ ew, float* __restrict__ b2) {
    int k = threadIdx.x;
    if (k < K) b2[k] = np_sumsq64(ew + (size_t)k * D);
}

// launch_bounds(512, 2): VGPR budget 256 so zr[64] + 4 accumulators stay
// resident. Occupancy is grid-limited (512 blocks = 2 blocks/CU = 16 waves/CU)
// so the old 64-VGPR/8-wave target bought nothing and cost a z-row reload
// per k-chunk through L1/L2 (~4 GB/dispatch of cache traffic).
__global__ __launch_bounds__(512, 2) void vq_main(
    const float* __restrict__ z, const float* __restrict__ ew,
    const float* __restrict__ b2, float* __restrict__ out,
    float* __restrict__ gsum, int* __restrict__ gcnt)
{
    __shared__ float s_bd[TOK_PER_BLK];
    __shared__ int   s_bk[TOK_PER_BLK];
    __shared__ int   s_cnt[K];

    const int tid  = threadIdx.x;
    const int half = tid >> 8;           // 0: codes 0..255, 1: codes 256..511
    const int lt   = tid & 255;
    const int token = blockIdx.x * TOK_PER_BLK + lt;

    s_cnt[tid] = 0;

    float zr[D];
    {
        const float4* zp = (const float4*)(z + (size_t)token * D);
        #pragma unroll
        for (int i = 0; i < 16; ++i) {
            float4 v = zp[i];
            zr[4*i] = v.x; zr[4*i+1] = v.y; zr[4*i+2] = v.z; zr[4*i+3] = v.w;
        }
    }

    // a_n = np.sum(z_n**2) in numpy's exact f32 order
    const float an = np_sumsq64(zr);

    // wave-uniform code range -> scalar loads for ew/b2
    const int k0 = __builtin_amdgcn_readfirstlane(half * 256);

    float bd = 1e30f;
    int   bk = 0;
    for (int k = k0; k < k0 + 256; k += 4) {
        const float* e0 = ew + (size_t)k * D;
        float g0 = 0.f, g1 = 0.f, g2 = 0.f, g3 = 0.f;
        #pragma unroll
        for (int d = 0; d < D; ++d) {
            g0 = fmaf(zr[d], e0[d],       g0);
            g1 = fmaf(zr[d], e0[D + d],   g1);
            g2 = fmaf(zr[d], e0[2*D + d], g2);
            g3 = fmaf(zr[d], e0[3*D + d], g3);
        }
        // d_k = fl( fl(a + b_k) - 2*g_k ); fmaf(-2,g,t) == fl(t - 2g) exactly
        float t0 = __fadd_rn(an, b2[k]);
        float t1 = __fadd_rn(an, b2[k+1]);
        float t2 = __fadd_rn(an, b2[k+2]);
        float t3 = __fadd_rn(an, b2[k+3]);
        float d0 = fmaf(-2.f, g0, t0);
        float d1 = fmaf(-2.f, g1, t1);
        float d2 = fmaf(-2.f, g2, t2);
        float d3 = fmaf(-2.f, g3, t3);
        // ascending k, strict <  ->  numpy argmin first-index semantics
        if (d0 < bd) { bd = d0; bk = k;     }
        if (d1 < bd) { bd = d1; bk = k + 1; }
        if (d2 < bd) { bd = d2; bk = k + 2; }
        if (d3 < bd) { bd = d3; bk = k + 3; }
    }

    if (half) { s_bd[lt] = bd; s_bk[lt] = bk; }
    __syncthreads();   // covers s_cnt init and s_bd/s_bk publish

    if (!half) {
        // strict <: on exact f32 tie keep half0 (lower index)
        if (s_bd[lt] < bd) { bd = s_bd[lt]; bk = s_bk[lt]; }

        atomicAdd(&s_cnt[bk], 1);

        // quantized_st = fl(z + fl(e - z)); accumulate sum (e-z)^2 for loss
        const float4* eq = (const float4*)(ew + (size_t)bk * D);
        float4* op = (float4*)(out + Q_OFF + (size_t)token * D);
        float sq = 0.f;
        #pragma unroll
        for (int i = 0; i < 16; ++i) {
            float4 e = eq[i];
            float zx = zr[4*i], zy = zr[4*i+1], zz = zr[4*i+2], zw = zr[4*i+3];
            float dx = e.x - zx, dy = e.y - zy, dz = e.z - zz, dw = e.w - zw;
            sq = fmaf(dx, dx, sq); sq = fmaf(dy, dy, sq);
            sq = fmaf(dz, dz, sq); sq = fmaf(dw, dw, sq);
            float4 o; o.x = zx + dx; o.y = zy + dy; o.z = zz + dz; o.w = zw + dw;
            op[i] = o;
        }
        out[ENC_OFF + token] = (float)bk;

        float mind = bd;   // min distance is the f32 quantized value itself
        #pragma unroll
        for (int off = 32; off; off >>= 1) {
            sq   += __shfl_down(sq, off);
            mind += __shfl_down(mind, off);
        }
        if ((tid & 63) == 0) {
            atomicAdd(&gsum[0], sq);
            atomicAdd(&gsum[1], mind);
        }
    }
    __syncthreads();

    int c = s_cnt[tid];
    if (c) atomicAdd(&gcnt[tid], c);
}

__global__ void vq_fin(const float* __restrict__ gsum, const int* __restrict__ gcnt,
                       float* __restrict__ out)
{
    __shared__ float red[8];
    int t = threadIdx.x;               // 512 threads, one per code
    float p = (float)gcnt[t] * (1.f / (float)N_TOK);
    float term = p * logf(p + 1e-10f);
    #pragma unroll
    for (int off = 32; off; off >>= 1) term += __shfl_down(term, off);
    if ((t & 63) == 0) red[t >> 6] = term;
    __syncthreads();
    if (t == 0) {
        float s = 0.f;
        #pragma unroll
        for (int i = 0; i < 8; ++i) s += red[i];
        out[PERP_OFF] = expf(-s);
        out[LOSS_OFF] = 1.25f * gsum[0] * (1.f / (float)(N_TOK * D));
        out[MIND_OFF] = gsum[1] * (1.f / (float)N_TOK);
    }
}

extern "C" void kernel_launch(void* const* d_in, const int* in_sizes, int n_in,
                              void* d_out, int out_size, void* d_ws, size_t ws_size,
                              hipStream_t stream)
{
    const float* z  = (const float*)d_in[0];
    const float* ew = (const float*)d_in[1];
    float* out = (float*)d_out;
    float* wsf = (float*)d_ws;

    float* gsum = wsf + 512;
    int*   gcnt = (int*)(wsf + 514);

    // zero S_sq, S_mind, counts each call (graph replays don't re-poison)
    hipMemsetAsync(wsf + 512, 0, 514 * sizeof(float), stream);

    vq_prep<<<1, 512, 0, stream>>>(ew, wsf);
    vq_main<<<N_TOK / TOK_PER_BLK, 512, 0, stream>>>(z, ew, wsf, out, gsum, gcnt);
    vq_fin<<<1, 512, 0, stream>>>(gsum, gcnt, out);
}

// Round 5
// 219.125 us; speedup vs baseline: 1.4375x; 1.4375x over previous
//
#include <hip/hip_runtime.h>
#include <math.h>

#define D 64
#define K 512
#define N_TOK (32 * 4096)            // 131072 tokens
#define TOK 128                      // tokens per block
#define BLK 256                      // threads per block (2 k-halves per token)

// output layout (all f32, concatenated in reference return order)
#define Q_OFF    0
#define LOSS_OFF 8388608
#define PERP_OFF 8388609
#define ENC_OFF  8388610
#define MIND_OFF 8519682

// ws layout (floats): [0..511] b2[k] = np-f32 sum(e_k^2) ; [512] S_sq ; [513] S_mind ; [514..1025] counts(int)

// numpy pairwise_sum, n=64, scalar 8-accumulator path, on fl(x_i*x_i).
__device__ __forceinline__ float np_sumsq64(const float* x) {
    float r[8];
    #pragma unroll
    for (int j = 0; j < 8; ++j) r[j] = __fmul_rn(x[j], x[j]);
    #pragma unroll
    for (int i = 8; i < 64; i += 8) {
        #pragma unroll
        for (int j = 0; j < 8; ++j)
            r[j] = __fadd_rn(r[j], __fmul_rn(x[i + j], x[i + j]));
    }
    float l = __fadd_rn(__fadd_rn(r[0], r[1]), __fadd_rn(r[2], r[3]));
    float h = __fadd_rn(__fadd_rn(r[4], r[5]), __fadd_rn(r[6], r[7]));
    return __fadd_rn(l, h);
}

__global__ void vq_prep(const float* __restrict__ ew, float* __restrict__ b2) {
    int k = threadIdx.x;
    if (k < K) b2[k] = np_sumsq64(ew + (size_t)k * D);
}

// z-tile lives in LDS, transposed [dc][token] with XOR swizzle so the
// compiler's preferred strategy (re-load the operand inside the k-loop
// instead of pinning 64 VGPRs) costs ds_read_b128 instead of a global
// round-trip. Per-thread live state is ~40 VGPRs.
__global__ __launch_bounds__(BLK) void vq_main(
    const float* __restrict__ z, const float* __restrict__ ew,
    const float* __restrict__ b2, float* __restrict__ out,
    float* __restrict__ gsum, int* __restrict__ gcnt)
{
    __shared__ float4 zl[16 * TOK];          // 32 KB, slot = dc*TOK + (tok ^ (dc&7))
    __shared__ float  s_bd[TOK];
    __shared__ int    s_bk[TOK];
    __shared__ int    s_cnt[K];

    const int tid = threadIdx.x;
    s_cnt[tid] = 0; s_cnt[tid + BLK] = 0;

    // ---- stage z tile: fully coalesced global read, swizzled LDS write ----
    {
        const float4* zg = (const float4*)z + (size_t)blockIdx.x * (TOK * 16);
        #pragma unroll
        for (int i = 0; i < 8; ++i) {
            int idx = i * BLK + tid;           // 0..2047 float4s of the tile
            float4 v = zg[idx];
            int tok = idx >> 4, dc = idx & 15;
            zl[dc * TOK + (tok ^ (dc & 7))] = v;
        }
    }
    __syncthreads();

    const int h = tid >> 7;                    // k-half
    const int t = tid & (TOK - 1);             // token within block

    int tx[8];
    #pragma unroll
    for (int j = 0; j < 8; ++j) tx[j] = t ^ j;

    // a_n = np.sum(z^2) in numpy's exact order, sourced from LDS
    float an;
    {
        float r[8];
        #pragma unroll
        for (int c = 0; c < 16; ++c) {
            float4 v = zl[c * TOK + tx[c & 7]];
            int j0 = (c & 1) * 4;
            if (c < 2) {
                r[j0]   = __fmul_rn(v.x, v.x); r[j0+1] = __fmul_rn(v.y, v.y);
                r[j0+2] = __fmul_rn(v.z, v.z); r[j0+3] = __fmul_rn(v.w, v.w);
            } else {
                r[j0]   = __fadd_rn(r[j0],   __fmul_rn(v.x, v.x));
                r[j0+1] = __fadd_rn(r[j0+1], __fmul_rn(v.y, v.y));
                r[j0+2] = __fadd_rn(r[j0+2], __fmul_rn(v.z, v.z));
                r[j0+3] = __fadd_rn(r[j0+3], __fmul_rn(v.w, v.w));
            }
        }
        float l = __fadd_rn(__fadd_rn(r[0], r[1]), __fadd_rn(r[2], r[3]));
        float hh = __fadd_rn(__fadd_rn(r[4], r[5]), __fadd_rn(r[6], r[7]));
        an = __fadd_rn(l, hh);
    }

    // ---- argmin over this half's 256 codes ----
    const int k0 = __builtin_amdgcn_readfirstlane(h * 256);

    float bd = 1e30f;
    int   bk = 0;
    for (int k = k0; k < k0 + 256; k += 4) {
        const float* e0 = ew + (size_t)k * D;   // wave-uniform -> s_load
        float a0 = 0.f, a1 = 0.f, a2 = 0.f, a3 = 0.f;
        #pragma unroll
        for (int dc = 0; dc < 16; ++dc) {
            float4 zv = zl[dc * TOK + tx[dc & 7]];
            a0 = fmaf(zv.x, e0[4*dc],       a0); a0 = fmaf(zv.y, e0[4*dc+1],       a0);
            a0 = fmaf(zv.z, e0[4*dc+2],     a0); a0 = fmaf(zv.w, e0[4*dc+3],       a0);
            a1 = fmaf(zv.x, e0[D+4*dc],     a1); a1 = fmaf(zv.y, e0[D+4*dc+1],     a1);
            a1 = fmaf(zv.z, e0[D+4*dc+2],   a1); a1 = fmaf(zv.w, e0[D+4*dc+3],     a1);
            a2 = fmaf(zv.x, e0[2*D+4*dc],   a2); a2 = fmaf(zv.y, e0[2*D+4*dc+1],   a2);
            a2 = fmaf(zv.z, e0[2*D+4*dc+2], a2); a2 = fmaf(zv.w, e0[2*D+4*dc+3],   a2);
            a3 = fmaf(zv.x, e0[3*D+4*dc],   a3); a3 = fmaf(zv.y, e0[3*D+4*dc+1],   a3);
            a3 = fmaf(zv.z, e0[3*D+4*dc+2], a3); a3 = fmaf(zv.w, e0[3*D+4*dc+3],   a3);
        }
        // d_k = fl( fl(a + b_k) - 2*g_k ); fmaf(-2,g,t) == fl(t - 2g) exactly
        float t0 = __fadd_rn(an, b2[k]);
        float t1 = __fadd_rn(an, b2[k+1]);
        float t2 = __fadd_rn(an, b2[k+2]);
        float t3 = __fadd_rn(an, b2[k+3]);
        float d0 = fmaf(-2.f, a0, t0);
        float d1 = fmaf(-2.f, a1, t1);
        float d2 = fmaf(-2.f, a2, t2);
        float d3 = fmaf(-2.f, a3, t3);
        // ascending k, strict <  ->  numpy argmin first-index semantics
        if (d0 < bd) { bd = d0; bk = k;     }
        if (d1 < bd) { bd = d1; bk = k + 1; }
        if (d2 < bd) { bd = d2; bk = k + 2; }
        if (d3 < bd) { bd = d3; bk = k + 3; }
    }

    if (h) { s_bd[t] = bd; s_bk[t] = bk; }
    __syncthreads();

    if (!h) {
        // strict <: on exact f32 tie keep half0 (lower index)
        if (s_bd[t] < bd) { bd = s_bd[t]; bk = s_bk[t]; }

        atomicAdd(&s_cnt[bk], 1);

        // quantized_st = fl(z + fl(e - z)); accumulate sum (e-z)^2 for loss
        const float4* eq = (const float4*)(ew + (size_t)bk * D);
        float4* op = (float4*)(out + Q_OFF + (size_t)(blockIdx.x * TOK + t) * D);
        float sq = 0.f;
        #pragma unroll
        for (int c = 0; c < 16; ++c) {
            float4 zv = zl[c * TOK + tx[c & 7]];
            float4 e = eq[c];
            float dx = e.x - zv.x, dy = e.y - zv.y;
            float dz = e.z - zv.z, dw = e.w - zv.w;
            sq = fmaf(dx, dx, sq); sq = fmaf(dy, dy, sq);
            sq = fmaf(dz, dz, sq); sq = fmaf(dw, dw, sq);
            float4 o; o.x = zv.x + dx; o.y = zv.y + dy; o.z = zv.z + dz; o.w = zv.w + dw;
            op[c] = o;
        }
        out[ENC_OFF + blockIdx.x * TOK + t] = (float)bk;

        float mind = bd;
        #pragma unroll
        for (int off = 32; off; off >>= 1) {
            sq   += __shfl_down(sq, off);
            mind += __shfl_down(mind, off);
        }
        if ((tid & 63) == 0) {
            atomicAdd(&gsum[0], sq);
            atomicAdd(&gsum[1], mind);
        }
    }
    __syncthreads();

    int c0 = s_cnt[tid];       if (c0) atomicAdd(&gcnt[tid], c0);
    int c1 = s_cnt[tid + BLK]; if (c1) atomicAdd(&gcnt[tid + BLK], c1);
}

__global__ void vq_fin(const float* __restrict__ gsum, const int* __restrict__ gcnt,
                       float* __restrict__ out)
{
    __shared__ float red[8];
    int t = threadIdx.x;               // 512 threads, one per code
    float p = (float)gcnt[t] * (1.f / (float)N_TOK);
    float term = p * logf(p + 1e-10f);
    #pragma unroll
    for (int off = 32; off; off >>= 1) term += __shfl_down(term, off);
    if ((t & 63) == 0) red[t >> 6] = term;
    __syncthreads();
    if (t == 0) {
        float s = 0.f;
        #pragma unroll
        for (int i = 0; i < 8; ++i) s += red[i];
        out[PERP_OFF] = expf(-s);
        out[LOSS_OFF] = 1.25f * gsum[0] * (1.f / (float)(N_TOK * D));
        out[MIND_OFF] = gsum[1] * (1.f / (float)N_TOK);
    }
}

extern "C" void kernel_launch(void* const* d_in, const int* in_sizes, int n_in,
                              void* d_out, int out_size, void* d_ws, size_t ws_size,
                              hipStream_t stream)
{
    const float* z  = (const float*)d_in[0];
    const float* ew = (const float*)d_in[1];
    float* out = (float*)d_out;
    float* wsf = (float*)d_ws;

    float* gsum = wsf + 512;
    int*   gcnt = (int*)(wsf + 514);

    // zero S_sq, S_mind, counts each call (graph replays don't re-poison)
    hipMemsetAsync(wsf + 512, 0, 514 * sizeof(float), stream);

    vq_prep<<<1, 512, 0, stream>>>(ew, wsf);
    vq_main<<<N_TOK / TOK, BLK, 0, stream>>>(z, ew, wsf, out, gsum, gcnt);
    vq_fin<<<1, 512, 0, stream>>>(gsum, gcnt, out);
}